// Round 8
// baseline (454.079 us; speedup 1.0000x reference)
//
#include <hip/hip_runtime.h>

typedef __attribute__((ext_vector_type(8))) short s16x8;
typedef __attribute__((ext_vector_type(4))) float f32x4;

__device__ __forceinline__ unsigned short f2bf(float x) {
  unsigned int u = __float_as_uint(x);
  u += 0x7FFFu + ((u >> 16) & 1u);
  return (unsigned short)(u >> 16);
}
__device__ __forceinline__ float bf2f(unsigned short h) {
  return __uint_as_float(((unsigned int)h) << 16);
}

__device__ __forceinline__ void gload16(const unsigned short* g, unsigned short* l) {
  __builtin_amdgcn_global_load_lds(
      (const __attribute__((address_space(1))) void*)g,
      (__attribute__((address_space(3))) void*)l, 16, 0, 0);
}

// ---------------- weights fp32 -> Wcat[2048][6144] = [Wlo | Whi] (bf16) ----------------
__global__ __launch_bounds__(256) void split_wcat(const float* __restrict__ src,
                                                  unsigned short* __restrict__ wcat) {
  int idx = blockIdx.x * 256 + threadIdx.x;  // 2048*384
  if (idx >= 2048 * 384) return;
  int seg = idx % 384, r = idx / 384;
  const float4* s = (const float4*)(src + (size_t)r * 3072 + seg * 8);
  float4 v0 = s[0], v1 = s[1];
  float f[8] = {v0.x, v0.y, v0.z, v0.w, v1.x, v1.y, v1.z, v1.w};
  unsigned short h8[8], l8[8];
#pragma unroll
  for (int i = 0; i < 8; ++i) {
    unsigned short h = f2bf(f[i]);
    h8[i] = h;
    l8[i] = f2bf(f[i] - bf2f(h));
  }
  *(uint4*)&wcat[(size_t)r * 6144 + seg * 8] = *(const uint4*)l8;          // lo
  *(uint4*)&wcat[(size_t)r * 6144 + 3072 + seg * 8] = *(const uint4*)h8;  // hi
}

// ---------------- patchify cropped -> Acat[1568][6144] = [Ahi | Alo] (bf16) ----------------
__global__ __launch_bounds__(256) void patchify_split(
    const float* __restrict__ src, unsigned short* __restrict__ acat) {
  int idx = blockIdx.x * 256 + threadIdx.x;  // 1568*384
  if (idx >= 1568 * 384) return;
  int kseg = idx % 384, row = idx / 384;
  int img = row / 49, pos = row % 49;
  int k = kseg * 8;
  int c = k >> 10, rem = k & 1023, r = rem >> 5, x0 = rem & 31;
  const float* s =
      src + ((size_t)(img * 3 + c) * 224 + (pos / 7) * 32 + r) * 224 +
      (pos % 7) * 32 + x0;
  float4 v0 = *(const float4*)(s);
  float4 v1 = *(const float4*)(s + 4);
  float f[8] = {v0.x, v0.y, v0.z, v0.w, v1.x, v1.y, v1.z, v1.w};
  unsigned short h8[8], l8[8];
#pragma unroll
  for (int i = 0; i < 8; ++i) {
    unsigned short h = f2bf(f[i]);
    h8[i] = h;
    l8[i] = f2bf(f[i] - bf2f(h));
  }
  *(uint4*)&acat[(size_t)row * 6144 + k] = *(const uint4*)h8;         // hi
  *(uint4*)&acat[(size_t)row * 6144 + 3072 + k] = *(const uint4*)l8;  // lo
}

// ---------------- window crop/resize -> patchified bf16 [9408][3072] ----------------
__global__ __launch_bounds__(256) void gather_windows(
    const float* __restrict__ img, const int* __restrict__ tl,
    unsigned short* __restrict__ win) {
  int idx = blockIdx.x * 256 + threadIdx.x;  // 9408*384
  if (idx >= 9408 * 384) return;
  int kseg = idx % 384, row = idx / 384;
  int w = row / 49, pos = row % 49;
  int b = w / 6, p = w % 6;
  int k = kseg * 8;
  int c = k >> 10, rem = k & 1023, r = rem >> 5, x0 = rem & 31;
  int y = (pos / 7) * 32 + r;
  int xb = (pos % 7) * 32 + x0;
  int tly = tl[(b * 6 + p) * 2 + 0];
  int tlx = tl[(b * 6 + p) * 2 + 1];
  const float* im = img + (size_t)(b * 3 + c) * 448 * 448;
  unsigned short o8[8];
  if (p < 3) {
    const float* s = im + (size_t)(tly + y) * 448 + tlx + xb;
#pragma unroll
    for (int i = 0; i < 8; ++i) o8[i] = f2bf(s[i]);
  } else {
    const float f = 111.0f / 223.0f;
    float sy = tly + y * f;
    int y0 = (int)floorf(sy);
    float wy = sy - (float)y0;
    int y1 = y0 + 1 < 447 ? y0 + 1 : 447;
    const float* r0p = im + (size_t)y0 * 448;
    const float* r1p = im + (size_t)y1 * 448;
#pragma unroll
    for (int i = 0; i < 8; ++i) {
      float sx = tlx + (xb + i) * f;
      int x0i = (int)floorf(sx);
      float wx = sx - (float)x0i;
      int x1i = x0i + 1 < 447 ? x0i + 1 : 447;
      float v0 = r0p[x0i] * (1.f - wy) + r1p[x0i] * wy;
      float v1 = r0p[x1i] * (1.f - wy) + r1p[x1i] * wy;
      o8[i] = f2bf(v0 * (1.f - wx) + v1 * wx);
    }
  }
  *(uint4*)&win[(size_t)row * 3072 + k] = *(const uint4*)o8;
}

// ---------------- batched tiled transpose: dst[C][R] = src[R][C] ----------------
__global__ __launch_bounds__(256) void transpose_kernel(
    const float* __restrict__ src, float* __restrict__ dst, int R, int C) {
  __shared__ float tile[32][33];
  int z = blockIdx.z;
  src += (size_t)z * R * C;
  dst += (size_t)z * R * C;
  int bx = blockIdx.x * 32, by = blockIdx.y * 32;
  int tx = threadIdx.x, ty = threadIdx.y;  // 32 x 8
#pragma unroll
  for (int i = 0; i < 32; i += 8) {
    int r = by + ty + i, c = bx + tx;
    if (r < R && c < C) tile[ty + i][tx] = src[r * C + c];
  }
  __syncthreads();
#pragma unroll
  for (int i = 0; i < 32; i += 8) {
    int r = bx + ty + i, c = by + tx;
    if (r < C && c < R) dst[r * R + c] = tile[tx][ty + i];
  }
}

// ---------------- conv GEMM (m97 structure, proven) ----------------
// MODE 0 (cropped): A=Acat[1568][6144]; z0: Ahi x Whi (kt=48), z1: [Ahi|Alo] x [Wlo|Whi]
//                   (kt=96) -> C planes 0/1.
// MODE 1 (windows): A=win[9408][3072], W=Whi half of Wcat; fused relu+GAP atomicAdd;
//                   1D grid with XCD-chunked swizzle.
template <int MODE>
__global__ __launch_bounds__(256) void gemm_conv(
    const unsigned short* __restrict__ A, const unsigned short* __restrict__ Wcat,
    float* __restrict__ C, float* __restrict__ embOut, int M) {
  constexpr int ldA = MODE ? 3072 : 6144;
  constexpr int ldW = 6144;
  __shared__ unsigned short sA[128 * 64];
  __shared__ unsigned short sB[128 * 64];
  const int t = threadIdx.x;
  int nb, mb, z, ktiles, Woff;
  if (MODE == 0) {
    nb = blockIdx.x; mb = blockIdx.y; z = blockIdx.z;
    ktiles = z ? 96 : 48;
    Woff = z ? 0 : 3072;
  } else {
    // XCD-chunked swizzle: consecutive hw ids (round-robin XCDs) -> contiguous chunk
    int nwg = gridDim.x, bid = blockIdx.x;
    int wg = (bid & 7) * (nwg >> 3) + (bid >> 3);
    mb = wg >> 4; nb = wg & 15;
    z = 0; ktiles = 48; Woff = 3072;
  }
  const int lane = t & 63;
  const int lr = lane & 15, lk = lane >> 4;
  const int wv = t >> 6;
  const int wqr = wv >> 1, wqc = wv & 1;

  const unsigned short* gA[4];
  unsigned short* lA[4];
  const unsigned short* gB[4];
  unsigned short* lB[4];
#pragma unroll
  for (int j = 0; j < 4; ++j) {
    int chunk = j * 256 + t;
    int row = chunk >> 3, seg = chunk & 7;
    int gseg = seg ^ (row & 7);
    int rg = mb * 128 + row;
    if (rg > M - 1) rg = M - 1;
    gA[j] = A + (size_t)rg * ldA + gseg * 8;
    lA[j] = &sA[chunk * 8];
    gB[j] = Wcat + (size_t)(nb * 128 + row) * ldW + Woff + gseg * 8;
    lB[j] = &sB[chunk * 8];
  }

  f32x4 acc[4][4] = {};
  for (int kb = 0; kb < ktiles; ++kb) {
    if (kb) __syncthreads();
#pragma unroll
    for (int j = 0; j < 4; ++j) {
      gload16(gA[j] + kb * 64, lA[j]);
      gload16(gB[j] + kb * 64, lB[j]);
    }
    __syncthreads();
#pragma unroll
    for (int ks = 0; ks < 2; ++ks) {
      s16x8 a[4], b[4];
#pragma unroll
      for (int m = 0; m < 4; ++m) {
        int row = wqr * 64 + m * 16 + lr;
        int seg = ks * 4 + lk;
        a[m] = *(const s16x8*)&sA[row * 64 + ((seg ^ (row & 7)) * 8)];
      }
#pragma unroll
      for (int n = 0; n < 4; ++n) {
        int row = wqc * 64 + n * 16 + lr;
        int seg = ks * 4 + lk;
        b[n] = *(const s16x8*)&sB[row * 64 + ((seg ^ (row & 7)) * 8)];
      }
#pragma unroll
      for (int m = 0; m < 4; ++m)
#pragma unroll
        for (int n = 0; n < 4; ++n)
          acc[m][n] =
              __builtin_amdgcn_mfma_f32_16x16x32_bf16(a[m], b[n], acc[m][n], 0, 0, 0);
    }
  }

  if (MODE == 1) {
    // relu + windowed GAP -> atomicAdd(emb[32+w][col], s/49)
#pragma unroll
    for (int m = 0; m < 4; ++m) {
      int base = mb * 128 + wqr * 64 + m * 16;
      if (base >= M) continue;
      int w0 = base / 49;
      int rtop = base + 15;
      if (rtop > M - 1) rtop = M - 1;
      int w1 = rtop / 49;
      for (int w = w0; w <= w1; ++w) {
#pragma unroll
        for (int n = 0; n < 4; ++n) {
          float s = 0.f;
#pragma unroll
          for (int e = 0; e < 4; ++e) {
            int r = base + lk * 4 + e;
            float v = acc[m][n][e];
            v = v > 0.f ? v : 0.f;
            s += (r < M && (r / 49) == w) ? v : 0.f;
          }
          s += __shfl_xor(s, 16, 64);
          s += __shfl_xor(s, 32, 64);
          if (lk == 0)
            atomicAdd(&embOut[(size_t)(32 + w) * 2048 + nb * 128 + wqc * 64 +
                              n * 16 + lr],
                      s * (1.0f / 49.0f));
        }
      }
    }
  } else {
#pragma unroll
    for (int m = 0; m < 4; ++m) {
      int rbase = mb * 128 + wqr * 64 + m * 16 + lk * 4;
#pragma unroll
      for (int e = 0; e < 4; ++e) {
        int r = rbase + e;
        if (r < M) {
#pragma unroll
          for (int n = 0; n < 4; ++n) {
            int c = nb * 128 + wqc * 64 + n * 16 + lr;
            C[(size_t)z * M * 2048 + (size_t)r * 2048 + c] = acc[m][n][e];
          }
        }
      }
    }
  }
}

// ---------------- cropped: sum 2 planes, relu, GAP->emb, fm wave-partials ----------------
__global__ __launch_bounds__(256) void crop_reduce(const float* __restrict__ P,
                                                   float* __restrict__ emb,
                                                   float* __restrict__ fmpart) {
  int b = blockIdx.x, cc = blockIdx.y, t = threadIdx.x;
  int c = cc * 256 + t;
  int lane = t & 63, wv = t >> 6;
  const size_t MN = (size_t)1568 * 2048;
  float colacc = 0.f;
  for (int pos = 0; pos < 49; ++pos) {
    size_t off = (size_t)(b * 49 + pos) * 2048 + c;
    float v = P[off] + P[MN + off];
    v = v > 0.f ? v : 0.f;
    colacc += v;
    float rp = v;
    for (int o = 1; o < 64; o <<= 1) rp += __shfl_xor(rp, o, 64);
    if (lane == 0) fmpart[(size_t)(b * 49 + pos) * 32 + cc * 4 + wv] = rp;
  }
  emb[(size_t)b * 2048 + c] = colacc / 49.0f;
}

// ---------------- coordinates (NMS peak picking) ----------------
__global__ void coords_kernel(const float* __restrict__ fmpart,
                              const float* __restrict__ scale,
                              int* __restrict__ tl) {
  int b = blockIdx.x, t = threadIdx.x;
  __shared__ float fs[49];
  if (t < 49) {
    const float* p = fmpart + (size_t)(b * 49 + t) * 32;
    float s = 0.f;
#pragma unroll
    for (int i = 0; i < 32; ++i) s += p[i];
    fs[t] = s;
  }
  __syncthreads();
  if (t != 0) return;
  int s0 = (int)scale[b * 2 + 0], s1 = (int)scale[b * 2 + 1];
  int smin = s0 < s1 ? s0 : s1;
  int base_y = (s0 - smin) / 2, base_x = (s1 - smin) / 2;
  float sc[36];
  for (int f = 0; f < 2; ++f) {
    int kk = (f == 0) ? 3 : 2;
    int sw = 8 - kk;
    int psz = (f == 0) ? 224 : 112;
    int half = psz / 2;
    for (int iy = 0; iy < sw; ++iy)
      for (int ix = 0; ix < sw; ++ix) {
        float s = 0.f;
        for (int dy = 0; dy < kk; ++dy)
          for (int dx = 0; dx < kk; ++dx) s += fs[(iy + dy) * 7 + ix + dx];
        sc[iy * sw + ix] = s / (float)(kk * kk);
      }
    for (int it = 0; it < 3; ++it) {
      float best = -1e30f;
      int bi = 0;
      for (int i = 0; i < sw * sw; ++i)
        if (sc[i] > best) { best = sc[i]; bi = i; }
      int ly = bi / sw, lx = bi % sw;
      for (int dy = -1; dy <= 1; ++dy)
        for (int dx = -1; dx <= 1; ++dx) {
          int ny = ly + dy, nx = lx + dx;
          if (ny >= 0 && ny < sw && nx >= 0 && nx < sw) sc[ny * sw + nx] = 0.f;
        }
      float rh = (2 * ly + 7 - sw + 1) / 14.0f;
      float rw = (2 * lx + 7 - sw + 1) / 14.0f;
      int cy = (int)(base_y + smin * rh);
      int cx = (int)(base_x + smin * rw);
      int tly = cy - half, bry = cy + half;
      int tlx = cx - half, brx = cx + half;
      int below = tly < 0 ? tly : 0; bry -= below; tly -= below;
      int over = bry - s0 > 0 ? bry - s0 : 0; tly -= over; bry -= over;
      tly = tly > 0 ? tly : 0;
      below = tlx < 0 ? tlx : 0; brx -= below; tlx -= below;
      over = brx - s1 > 0 ? brx - s1 : 0; tlx -= over; brx -= over;
      tlx = tlx > 0 ? tlx : 0;
      int slot = f * 3 + it;
      tl[(b * 6 + slot) * 2 + 0] = tly;
      tl[(b * 6 + slot) * 2 + 1] = tlx;
    }
  }
}

// ---------------- fc1 + relu + reorg to all_emb[32,7,128] ----------------
__global__ __launch_bounds__(512) void fc1_kernel(const float* __restrict__ emb,
                                                  const float* __restrict__ wT,
                                                  const float* __restrict__ bias,
                                                  float* __restrict__ all_emb) {
  int i = blockIdx.x;
  __shared__ float e[2048];
  int t = threadIdx.x;
  ((float4*)e)[t] = ((const float4*)(emb + (size_t)i * 2048))[t];
  __syncthreads();
  int wv = t >> 6, lane = t & 63;
  int c_off = lane & 15, kq = lane >> 4;
  int c = wv * 16 + c_off;
  float s = 0.f;
  const float* wp = wT + (size_t)kq * 512 * 128 + c;
  const float4* ep = (const float4*)(e + kq * 512);
#pragma unroll 4
  for (int j = 0; j < 128; ++j) {
    float4 ev = ep[j];
    s = fmaf(ev.x, wp[(4 * j + 0) * 128], s);
    s = fmaf(ev.y, wp[(4 * j + 1) * 128], s);
    s = fmaf(ev.z, wp[(4 * j + 2) * 128], s);
    s = fmaf(ev.w, wp[(4 * j + 3) * 128], s);
  }
  s += __shfl_xor(s, 16, 64);
  s += __shfl_xor(s, 32, 64);
  if (lane < 16) {
    float v = s + bias[c];
    v = v > 0.f ? v : 0.f;
    int dst;
    if (i < 32) dst = i * 7 + 6;
    else { int wd = i - 32; dst = (wd / 6) * 7 + (wd % 6); }
    all_emb[dst * 128 + c] = v;
  }
}

// ---------------- gemm7 helper for SA ----------------
template <int NCOLS, int RELU, bool RES>
__device__ __forceinline__ void gemm7(const float* __restrict__ X,
                                      const float* __restrict__ WT,
                                      const float* __restrict__ bias,
                                      const float* __restrict__ res,
                                      float* __restrict__ Y, int t) {
  int wv = t >> 6, lane = t & 63;
  int c_off = lane & 15, kq = lane >> 4;
  const int NCH = NCOLS / 16;
  for (int ch = wv; ch < NCH; ch += 16) {
    int c = ch * 16 + c_off;
    float s[7] = {0.f, 0.f, 0.f, 0.f, 0.f, 0.f, 0.f};
    const float* wp = WT + kq * 32 * NCOLS + c;
#pragma unroll 4
    for (int j = 0; j < 8; ++j) {
      float w0 = wp[(4 * j + 0) * NCOLS];
      float w1 = wp[(4 * j + 1) * NCOLS];
      float w2 = wp[(4 * j + 2) * NCOLS];
      float w3 = wp[(4 * j + 3) * NCOLS];
#pragma unroll
      for (int l = 0; l < 7; ++l) {
        float4 xv = *(const float4*)&X[l * 128 + kq * 32 + 4 * j];
        s[l] = fmaf(xv.x, w0, s[l]);
        s[l] = fmaf(xv.y, w1, s[l]);
        s[l] = fmaf(xv.z, w2, s[l]);
        s[l] = fmaf(xv.w, w3, s[l]);
      }
    }
#pragma unroll
    for (int l = 0; l < 7; ++l) {
      s[l] += __shfl_xor(s[l], 16, 64);
      s[l] += __shfl_xor(s[l], 32, 64);
    }
    if (lane < 16) {
      float bv = bias[c];
#pragma unroll
      for (int l = 0; l < 7; ++l) {
        float v = s[l] + bv;
        if (RES) v += res[l * 128 + c];
        if (RELU) v = v > 0.f ? v : 0.f;
        Y[l * NCOLS + c] = v;
      }
    }
  }
}

// ---------------- 3x SA layers + final fc ----------------
__global__ __launch_bounds__(1024) void sa_kernel(
    const float* __restrict__ all_emb, const float* __restrict__ inT,
    const float* __restrict__ in_b, const float* __restrict__ outT,
    const float* __restrict__ out_b, const float* __restrict__ ln1w,
    const float* __restrict__ ln1b, const float* __restrict__ f1T,
    const float* __restrict__ f1b, const float* __restrict__ f2T,
    const float* __restrict__ f2b, const float* __restrict__ ln2w,
    const float* __restrict__ ln2b, const float* __restrict__ fcw,
    const float* __restrict__ fcb, float* __restrict__ out) {
  int b = blockIdx.x, t = threadIdx.x;
  __shared__ float x[7][128], qkv[7][384], att[4][7][7], ybuf[7][128], tmp[7][128];
  __shared__ float mu[7], inv[7];
  if (t < 896) x[t / 128][t % 128] = all_emb[b * 896 + t];
  __syncthreads();
  for (int layer = 0; layer < 3; ++layer) {
    gemm7<384, 0, false>(&x[0][0], inT + layer * 384 * 128, in_b + layer * 384,
                         nullptr, &qkv[0][0], t);
    __syncthreads();
    if (t < 196) {
      int h = t / 49, l = (t % 49) / 7, m = t % 7;
      const float4* qr = (const float4*)&qkv[l][h * 32];
      const float4* kr = (const float4*)&qkv[m][128 + h * 32];
      float s = 0.f;
#pragma unroll
      for (int d = 0; d < 8; ++d) {
        float4 a = qr[d], c = kr[d];
        s += a.x * c.x + a.y * c.y + a.z * c.z + a.w * c.w;
      }
      att[h][l][m] = s * 0.17677669529663687f;
    }
    __syncthreads();
    if (t < 28) {
      int h = t / 7, l = t % 7;
      float mx = att[h][l][0];
      for (int m = 1; m < 7; ++m) mx = fmaxf(mx, att[h][l][m]);
      float s = 0.f;
      float e[7];
      for (int m = 0; m < 7; ++m) { e[m] = expf(att[h][l][m] - mx); s += e[m]; }
      float r = 1.0f / s;
      for (int m = 0; m < 7; ++m) att[h][l][m] = e[m] * r;
    }
    __syncthreads();
    if (t < 896) {
      int l = t / 128, d = t % 128, h = d / 32;
      float s = 0.f;
#pragma unroll
      for (int m = 0; m < 7; ++m) s += att[h][l][m] * qkv[m][256 + d];
      ybuf[l][d] = s;
    }
    __syncthreads();
    gemm7<128, 0, true>(&ybuf[0][0], outT + layer * 128 * 128,
                        out_b + layer * 128, &x[0][0], &tmp[0][0], t);
    __syncthreads();
    if (t < 448) {
      int row = t >> 6, lane = t & 63;
      float a = tmp[row][lane], c2 = tmp[row][lane + 64];
      float s = a + c2;
      for (int o = 1; o < 64; o <<= 1) s += __shfl_xor(s, o, 64);
      float m = s * (1.0f / 128.0f);
      float d1 = a - m, d2 = c2 - m;
      float v = d1 * d1 + d2 * d2;
      for (int o = 1; o < 64; o <<= 1) v += __shfl_xor(v, o, 64);
      if (lane == 0) { mu[row] = m; inv[row] = 1.0f / sqrtf(v * (1.0f / 128.0f) + 1e-5f); }
    }
    __syncthreads();
    if (t < 896) {
      int l = t / 128, d = t % 128;
      x[l][d] = (tmp[l][d] - mu[l]) * inv[l] * ln1w[layer * 128 + d] +
                ln1b[layer * 128 + d];
    }
    __syncthreads();
    gemm7<128, 1, false>(&x[0][0], f1T + layer * 128 * 128, f1b + layer * 128,
                         nullptr, &ybuf[0][0], t);
    __syncthreads();
    gemm7<128, 0, true>(&ybuf[0][0], f2T + layer * 128 * 128, f2b + layer * 128,
                        &x[0][0], &tmp[0][0], t);
    __syncthreads();
    if (t < 448) {
      int row = t >> 6, lane = t & 63;
      float a = tmp[row][lane], c2 = tmp[row][lane + 64];
      float s = a + c2;
      for (int o = 1; o < 64; o <<= 1) s += __shfl_xor(s, o, 64);
      float m = s * (1.0f / 128.0f);
      float d1 = a - m, d2 = c2 - m;
      float v = d1 * d1 + d2 * d2;
      for (int o = 1; o < 64; o <<= 1) v += __shfl_xor(v, o, 64);
      if (lane == 0) { mu[row] = m; inv[row] = 1.0f / sqrtf(v * (1.0f / 128.0f) + 1e-5f); }
    }
    __syncthreads();
    if (t < 896) {
      int l = t / 128, d = t % 128;
      x[l][d] = (tmp[l][d] - mu[l]) * inv[l] * ln2w[layer * 128 + d] +
                ln2b[layer * 128 + d];
    }
    __syncthreads();
  }
  if (t < 64) {
    float s = x[6][t] * fcw[t] + x[6][t + 64] * fcw[t + 64];
    for (int o = 1; o < 64; o <<= 1) s += __shfl_xor(s, o, 64);
    if (t == 0) out[b] = s + fcb[0];
  }
}

extern "C" void kernel_launch(void* const* d_in, const int* in_sizes, int n_in,
                              void* d_out, int out_size, void* d_ws, size_t ws_size,
                              hipStream_t stream) {
  (void)in_sizes; (void)n_in; (void)out_size; (void)ws_size;
  const float* input_img = (const float*)d_in[0];
  const float* cropped = (const float*)d_in[1];
  const float* scale = (const float*)d_in[2];
  const float* conv_w = (const float*)d_in[3];
  const float* fc1_w = (const float*)d_in[4];
  const float* fc1_b = (const float*)d_in[5];
  const float* fc_w = (const float*)d_in[6];
  const float* fc_b = (const float*)d_in[7];
  const float* sa_in_w = (const float*)d_in[8];
  const float* sa_in_b = (const float*)d_in[9];
  const float* sa_out_w = (const float*)d_in[10];
  const float* sa_out_b = (const float*)d_in[11];
  const float* sa_ln1_w = (const float*)d_in[12];
  const float* sa_ln1_b = (const float*)d_in[13];
  const float* sa_fc1_w = (const float*)d_in[14];
  const float* sa_fc1_b = (const float*)d_in[15];
  const float* sa_fc2_w = (const float*)d_in[16];
  const float* sa_fc2_b = (const float*)d_in[17];
  const float* sa_ln2_w = (const float*)d_in[18];
  const float* sa_ln2_b = (const float*)d_in[19];

  char* ws = (char*)d_ws;
  size_t off = 0;
  auto alloc = [&](size_t bytes) -> void* {
    void* p = ws + off;
    off = (off + bytes + 255) & ~(size_t)255;
    return p;
  };
  unsigned short* wcat = (unsigned short*)alloc(2048L * 6144 * 2);
  unsigned short* acat = (unsigned short*)alloc(1568L * 6144 * 2);
  unsigned short* winbuf = (unsigned short*)alloc(9408L * 3072 * 2);
  float* Cpart = (float*)alloc(2L * 1568 * 2048 * 4);
  float* emb = (float*)alloc(224L * 2048 * 4);
  float* fmpart = (float*)alloc(1568L * 32 * 4);
  int* tlbuf = (int*)alloc(32L * 6 * 2 * 4);
  float* all_emb = (float*)alloc(32L * 7 * 128 * 4);
  float* fc1T = (float*)alloc(2048L * 128 * 4);
  float* inT = (float*)alloc(3L * 384 * 128 * 4);
  float* outT = (float*)alloc(3L * 128 * 128 * 4);
  float* f1T = (float*)alloc(3L * 128 * 128 * 4);
  float* f2T = (float*)alloc(3L * 128 * 128 * 4);

  // zero windows-GAP accumulation region (emb rows 32..223)
  hipMemsetAsync(emb + 32 * 2048, 0, 192L * 2048 * 4, stream);

  split_wcat<<<3072, 256, 0, stream>>>(conv_w, wcat);
  patchify_split<<<2352, 256, 0, stream>>>(cropped, acat);

  dim3 tb(32, 8);
  transpose_kernel<<<dim3(64, 4, 1), tb, 0, stream>>>(fc1_w, fc1T, 128, 2048);
  transpose_kernel<<<dim3(4, 12, 3), tb, 0, stream>>>(sa_in_w, inT, 384, 128);
  transpose_kernel<<<dim3(4, 4, 3), tb, 0, stream>>>(sa_out_w, outT, 128, 128);
  transpose_kernel<<<dim3(4, 4, 3), tb, 0, stream>>>(sa_fc1_w, f1T, 128, 128);
  transpose_kernel<<<dim3(4, 4, 3), tb, 0, stream>>>(sa_fc2_w, f2T, 128, 128);

  // cropped conv: z0 = Ahi*Whi, z1 = Ahi*Wlo + Alo*Whi (K-concat), 2 C planes
  gemm_conv<0><<<dim3(16, 13, 2), 256, 0, stream>>>(acat, wcat, Cpart, nullptr, 1568);
  crop_reduce<<<dim3(32, 8), 256, 0, stream>>>(Cpart, emb, fmpart);
  coords_kernel<<<32, 64, 0, stream>>>(fmpart, scale, tlbuf);
  gather_windows<<<14112, 256, 0, stream>>>(input_img, tlbuf, winbuf);
  // windows conv: single bf16 pass, fused relu+GAP, XCD-chunked swizzle (1184%8==0)
  gemm_conv<1><<<1184, 256, 0, stream>>>(winbuf, wcat, nullptr, emb, 9408);
  fc1_kernel<<<224, 512, 0, stream>>>(emb, fc1T, fc1_b, all_emb);
  sa_kernel<<<32, 1024, 0, stream>>>(all_emb, inT, sa_in_b, outT, sa_out_b,
                                     sa_ln1_w, sa_ln1_b, f1T, sa_fc1_b,
                                     f2T, sa_fc2_b, sa_ln2_w, sa_ln2_b,
                                     fc_w, fc_b, (float*)d_out);
}

// Round 9
// 421.812 us; speedup vs baseline: 1.0765x; 1.0765x over previous
//
#include <hip/hip_runtime.h>

typedef __attribute__((ext_vector_type(8))) short s16x8;
typedef __attribute__((ext_vector_type(4))) float f32x4;

__device__ __forceinline__ unsigned short f2bf(float x) {
  unsigned int u = __float_as_uint(x);
  u += 0x7FFFu + ((u >> 16) & 1u);
  return (unsigned short)(u >> 16);
}
__device__ __forceinline__ float bf2f(unsigned short h) {
  return __uint_as_float(((unsigned int)h) << 16);
}

__device__ __forceinline__ void gload16(const unsigned short* g, unsigned short* l) {
  __builtin_amdgcn_global_load_lds(
      (const __attribute__((address_space(1))) void*)g,
      (__attribute__((address_space(3))) void*)l, 16, 0, 0);
}

// ---------------- weights fp32 -> Wcat[2048][6144] = [Wlo | Whi] (bf16) ----------------
__global__ __launch_bounds__(256) void split_wcat(const float* __restrict__ src,
                                                  unsigned short* __restrict__ wcat) {
  int idx = blockIdx.x * 256 + threadIdx.x;  // 2048*384
  if (idx >= 2048 * 384) return;
  int seg = idx % 384, r = idx / 384;
  const float4* s = (const float4*)(src + (size_t)r * 3072 + seg * 8);
  float4 v0 = s[0], v1 = s[1];
  float f[8] = {v0.x, v0.y, v0.z, v0.w, v1.x, v1.y, v1.z, v1.w};
  unsigned short h8[8], l8[8];
#pragma unroll
  for (int i = 0; i < 8; ++i) {
    unsigned short h = f2bf(f[i]);
    h8[i] = h;
    l8[i] = f2bf(f[i] - bf2f(h));
  }
  *(uint4*)&wcat[(size_t)r * 6144 + seg * 8] = *(const uint4*)l8;          // lo
  *(uint4*)&wcat[(size_t)r * 6144 + 3072 + seg * 8] = *(const uint4*)h8;  // hi
}

// ---------------- patchify cropped -> Acat[1568][6144] = [Ahi | Alo] (bf16) ----------------
__global__ __launch_bounds__(256) void patchify_split(
    const float* __restrict__ src, unsigned short* __restrict__ acat) {
  int idx = blockIdx.x * 256 + threadIdx.x;  // 1568*384
  if (idx >= 1568 * 384) return;
  int kseg = idx % 384, row = idx / 384;
  int img = row / 49, pos = row % 49;
  int k = kseg * 8;
  int c = k >> 10, rem = k & 1023, r = rem >> 5, x0 = rem & 31;
  const float* s =
      src + ((size_t)(img * 3 + c) * 224 + (pos / 7) * 32 + r) * 224 +
      (pos % 7) * 32 + x0;
  float4 v0 = *(const float4*)(s);
  float4 v1 = *(const float4*)(s + 4);
  float f[8] = {v0.x, v0.y, v0.z, v0.w, v1.x, v1.y, v1.z, v1.w};
  unsigned short h8[8], l8[8];
#pragma unroll
  for (int i = 0; i < 8; ++i) {
    unsigned short h = f2bf(f[i]);
    h8[i] = h;
    l8[i] = f2bf(f[i] - bf2f(h));
  }
  *(uint4*)&acat[(size_t)row * 6144 + k] = *(const uint4*)h8;         // hi
  *(uint4*)&acat[(size_t)row * 6144 + 3072 + k] = *(const uint4*)l8;  // lo
}

// ---------------- window crop/resize -> patchified bf16 [9408][3072] ----------------
__global__ __launch_bounds__(256) void gather_windows(
    const float* __restrict__ img, const int* __restrict__ tl,
    unsigned short* __restrict__ win) {
  int idx = blockIdx.x * 256 + threadIdx.x;  // 9408*384
  if (idx >= 9408 * 384) return;
  int kseg = idx % 384, row = idx / 384;
  int w = row / 49, pos = row % 49;
  int b = w / 6, p = w % 6;
  int k = kseg * 8;
  int c = k >> 10, rem = k & 1023, r = rem >> 5, x0 = rem & 31;
  int y = (pos / 7) * 32 + r;
  int xb = (pos % 7) * 32 + x0;
  int tly = tl[(b * 6 + p) * 2 + 0];
  int tlx = tl[(b * 6 + p) * 2 + 1];
  const float* im = img + (size_t)(b * 3 + c) * 448 * 448;
  unsigned short o8[8];
  if (p < 3) {
    const float* s = im + (size_t)(tly + y) * 448 + tlx + xb;
#pragma unroll
    for (int i = 0; i < 8; ++i) o8[i] = f2bf(s[i]);
  } else {
    const float f = 111.0f / 223.0f;
    float sy = tly + y * f;
    int y0 = (int)floorf(sy);
    float wy = sy - (float)y0;
    int y1 = y0 + 1 < 447 ? y0 + 1 : 447;
    const float* r0p = im + (size_t)y0 * 448;
    const float* r1p = im + (size_t)y1 * 448;
#pragma unroll
    for (int i = 0; i < 8; ++i) {
      float sx = tlx + (xb + i) * f;
      int x0i = (int)floorf(sx);
      float wx = sx - (float)x0i;
      int x1i = x0i + 1 < 447 ? x0i + 1 : 447;
      float v0 = r0p[x0i] * (1.f - wy) + r1p[x0i] * wy;
      float v1 = r0p[x1i] * (1.f - wy) + r1p[x1i] * wy;
      o8[i] = f2bf(v0 * (1.f - wx) + v1 * wx);
    }
  }
  *(uint4*)&win[(size_t)row * 3072 + k] = *(const uint4*)o8;
}

// ---------------- all weight transposes in ONE dispatch (544 blocks) ----------------
__global__ __launch_bounds__(256) void transpose_all(
    const float* __restrict__ fc1_w, float* __restrict__ fc1T,
    const float* __restrict__ in_w, float* __restrict__ inT,
    const float* __restrict__ out_w, float* __restrict__ outT,
    const float* __restrict__ f1w, float* __restrict__ f1T,
    const float* __restrict__ f2w, float* __restrict__ f2T) {
  __shared__ float tile[32][33];
  int id = blockIdx.x;
  const float* src;
  float* dst;
  int R, C, bx, by;
  if (id < 256) {
    src = fc1_w; dst = fc1T; R = 128; C = 2048; bx = id % 64; by = id / 64;
  } else if (id < 400) {
    id -= 256;
    int z = id / 48, r = id % 48;
    src = in_w + z * 384 * 128; dst = inT + z * 384 * 128;
    R = 384; C = 128; bx = r % 4; by = r / 4;
  } else {
    id -= 400;
    int which = id / 48;  // 0=out, 1=f1, 2=f2
    id -= which * 48;
    int z = id / 16, r = id % 16;
    const float* s3[3] = {out_w, f1w, f2w};
    float* d3[3] = {outT, f1T, f2T};
    src = s3[which] + z * 128 * 128; dst = d3[which] + z * 128 * 128;
    R = 128; C = 128; bx = r % 4; by = r / 4;
  }
  int t = threadIdx.x;
  int tx = t & 31, ty = t >> 5;  // 32 x 8
#pragma unroll
  for (int i = 0; i < 32; i += 8) {
    int r = by * 32 + ty + i, c = bx * 32 + tx;
    if (r < R && c < C) tile[ty + i][tx] = src[(size_t)r * C + c];
  }
  __syncthreads();
#pragma unroll
  for (int i = 0; i < 32; i += 8) {
    int r = bx * 32 + ty + i, c = by * 32 + tx;
    if (r < C && c < R) dst[(size_t)r * R + c] = tile[tx][ty + i];
  }
}

// ---------------- conv GEMM (m97 structure, round-7 proven mapping) ----------------
// MODE 0 (cropped): grid (16,13,3); z0=Ahi*Whi, z1=Ahi*Wlo, z2=Alo*Whi; 48 kt each;
//                   writes C plane z.
// MODE 1 (windows): grid (16,74); A=win[9408][3072] x Whi; fused relu+GAP atomicAdd.
template <int MODE>
__global__ __launch_bounds__(256) void gemm_conv(
    const unsigned short* __restrict__ A, const unsigned short* __restrict__ Wcat,
    float* __restrict__ C, float* __restrict__ embOut, int M) {
  constexpr int ldA = MODE ? 3072 : 6144;
  __shared__ unsigned short sA[128 * 64];
  __shared__ unsigned short sB[128 * 64];
  const int t = threadIdx.x;
  const int nb = blockIdx.x, mb = blockIdx.y;
  const int z = MODE ? 0 : blockIdx.z;
  const int Aoff = (MODE == 0 && z == 2) ? 3072 : 0;
  const int Woff = (MODE == 0 && z == 1) ? 0 : 3072;
  const int lane = t & 63;
  const int lr = lane & 15, lk = lane >> 4;
  const int wv = t >> 6;
  const int wqr = wv >> 1, wqc = wv & 1;

  const unsigned short* gA[4];
  unsigned short* lA[4];
  const unsigned short* gB[4];
  unsigned short* lB[4];
#pragma unroll
  for (int j = 0; j < 4; ++j) {
    int chunk = j * 256 + t;
    int row = chunk >> 3, seg = chunk & 7;
    int gseg = seg ^ (row & 7);
    int rg = mb * 128 + row;
    if (rg > M - 1) rg = M - 1;
    gA[j] = A + (size_t)rg * ldA + Aoff + gseg * 8;
    lA[j] = &sA[chunk * 8];
    gB[j] = Wcat + (size_t)(nb * 128 + row) * 6144 + Woff + gseg * 8;
    lB[j] = &sB[chunk * 8];
  }

  f32x4 acc[4][4] = {};
  for (int kb = 0; kb < 48; ++kb) {
    if (kb) __syncthreads();
#pragma unroll
    for (int j = 0; j < 4; ++j) {
      gload16(gA[j] + kb * 64, lA[j]);
      gload16(gB[j] + kb * 64, lB[j]);
    }
    __syncthreads();
#pragma unroll
    for (int ks = 0; ks < 2; ++ks) {
      s16x8 a[4], b[4];
#pragma unroll
      for (int m = 0; m < 4; ++m) {
        int row = wqr * 64 + m * 16 + lr;
        int seg = ks * 4 + lk;
        a[m] = *(const s16x8*)&sA[row * 64 + ((seg ^ (row & 7)) * 8)];
      }
#pragma unroll
      for (int n = 0; n < 4; ++n) {
        int row = wqc * 64 + n * 16 + lr;
        int seg = ks * 4 + lk;
        b[n] = *(const s16x8*)&sB[row * 64 + ((seg ^ (row & 7)) * 8)];
      }
#pragma unroll
      for (int m = 0; m < 4; ++m)
#pragma unroll
        for (int n = 0; n < 4; ++n)
          acc[m][n] =
              __builtin_amdgcn_mfma_f32_16x16x32_bf16(a[m], b[n], acc[m][n], 0, 0, 0);
    }
  }

  if (MODE == 1) {
    // relu + windowed GAP -> atomicAdd(emb[32+w][col], s/49)
#pragma unroll
    for (int m = 0; m < 4; ++m) {
      int base = mb * 128 + wqr * 64 + m * 16;
      if (base >= M) continue;
      int w0 = base / 49;
      int rtop = base + 15;
      if (rtop > M - 1) rtop = M - 1;
      int w1 = rtop / 49;
      for (int w = w0; w <= w1; ++w) {
#pragma unroll
        for (int n = 0; n < 4; ++n) {
          float s = 0.f;
#pragma unroll
          for (int e = 0; e < 4; ++e) {
            int r = base + lk * 4 + e;
            float v = acc[m][n][e];
            v = v > 0.f ? v : 0.f;
            s += (r < M && (r / 49) == w) ? v : 0.f;
          }
          s += __shfl_xor(s, 16, 64);
          s += __shfl_xor(s, 32, 64);
          if (lk == 0)
            atomicAdd(&embOut[(size_t)(32 + w) * 2048 + nb * 128 + wqc * 64 +
                              n * 16 + lr],
                      s * (1.0f / 49.0f));
        }
      }
    }
  } else {
#pragma unroll
    for (int m = 0; m < 4; ++m) {
      int rbase = mb * 128 + wqr * 64 + m * 16 + lk * 4;
#pragma unroll
      for (int e = 0; e < 4; ++e) {
        int r = rbase + e;
        if (r < M) {
#pragma unroll
          for (int n = 0; n < 4; ++n) {
            int c = nb * 128 + wqc * 64 + n * 16 + lr;
            C[(size_t)z * M * 2048 + (size_t)r * 2048 + c] = acc[m][n][e];
          }
        }
      }
    }
  }
}

// ---------------- cropped: sum 3 planes, relu, GAP->emb, fm wave-partials ----------------
__global__ __launch_bounds__(256) void crop_reduce(const float* __restrict__ P,
                                                   float* __restrict__ emb,
                                                   float* __restrict__ fmpart) {
  int b = blockIdx.x, cc = blockIdx.y, t = threadIdx.x;
  int c = cc * 256 + t;
  int lane = t & 63, wv = t >> 6;
  const size_t MN = (size_t)1568 * 2048;
  float colacc = 0.f;
  for (int pos = 0; pos < 49; ++pos) {
    size_t off = (size_t)(b * 49 + pos) * 2048 + c;
    float v = P[off] + P[MN + off] + P[2 * MN + off];
    v = v > 0.f ? v : 0.f;
    colacc += v;
    float rp = v;
    for (int o = 1; o < 64; o <<= 1) rp += __shfl_xor(rp, o, 64);
    if (lane == 0) fmpart[(size_t)(b * 49 + pos) * 32 + cc * 4 + wv] = rp;
  }
  emb[(size_t)b * 2048 + c] = colacc / 49.0f;
}

// ---------------- coordinates (NMS peak picking) ----------------
__global__ void coords_kernel(const float* __restrict__ fmpart,
                              const float* __restrict__ scale,
                              int* __restrict__ tl) {
  int b = blockIdx.x, t = threadIdx.x;
  __shared__ float fs[49];
  if (t < 49) {
    const float* p = fmpart + (size_t)(b * 49 + t) * 32;
    float s = 0.f;
#pragma unroll
    for (int i = 0; i < 32; ++i) s += p[i];
    fs[t] = s;
  }
  __syncthreads();
  if (t != 0) return;
  int s0 = (int)scale[b * 2 + 0], s1 = (int)scale[b * 2 + 1];
  int smin = s0 < s1 ? s0 : s1;
  int base_y = (s0 - smin) / 2, base_x = (s1 - smin) / 2;
  float sc[36];
  for (int f = 0; f < 2; ++f) {
    int kk = (f == 0) ? 3 : 2;
    int sw = 8 - kk;
    int psz = (f == 0) ? 224 : 112;
    int half = psz / 2;
    for (int iy = 0; iy < sw; ++iy)
      for (int ix = 0; ix < sw; ++ix) {
        float s = 0.f;
        for (int dy = 0; dy < kk; ++dy)
          for (int dx = 0; dx < kk; ++dx) s += fs[(iy + dy) * 7 + ix + dx];
        sc[iy * sw + ix] = s / (float)(kk * kk);
      }
    for (int it = 0; it < 3; ++it) {
      float best = -1e30f;
      int bi = 0;
      for (int i = 0; i < sw * sw; ++i)
        if (sc[i] > best) { best = sc[i]; bi = i; }
      int ly = bi / sw, lx = bi % sw;
      for (int dy = -1; dy <= 1; ++dy)
        for (int dx = -1; dx <= 1; ++dx) {
          int ny = ly + dy, nx = lx + dx;
          if (ny >= 0 && ny < sw && nx >= 0 && nx < sw) sc[ny * sw + nx] = 0.f;
        }
      float rh = (2 * ly + 7 - sw + 1) / 14.0f;
      float rw = (2 * lx + 7 - sw + 1) / 14.0f;
      int cy = (int)(base_y + smin * rh);
      int cx = (int)(base_x + smin * rw);
      int tly = cy - half, bry = cy + half;
      int tlx = cx - half, brx = cx + half;
      int below = tly < 0 ? tly : 0; bry -= below; tly -= below;
      int over = bry - s0 > 0 ? bry - s0 : 0; tly -= over; bry -= over;
      tly = tly > 0 ? tly : 0;
      below = tlx < 0 ? tlx : 0; brx -= below; tlx -= below;
      over = brx - s1 > 0 ? brx - s1 : 0; tlx -= over; brx -= over;
      tlx = tlx > 0 ? tlx : 0;
      int slot = f * 3 + it;
      tl[(b * 6 + slot) * 2 + 0] = tly;
      tl[(b * 6 + slot) * 2 + 1] = tlx;
    }
  }
}

// ---------------- fc1 + relu + reorg to all_emb[32,7,128] ----------------
__global__ __launch_bounds__(512) void fc1_kernel(const float* __restrict__ emb,
                                                  const float* __restrict__ wT,
                                                  const float* __restrict__ bias,
                                                  float* __restrict__ all_emb) {
  int i = blockIdx.x;
  __shared__ float e[2048];
  int t = threadIdx.x;
  ((float4*)e)[t] = ((const float4*)(emb + (size_t)i * 2048))[t];
  __syncthreads();
  int wv = t >> 6, lane = t & 63;
  int c_off = lane & 15, kq = lane >> 4;
  int c = wv * 16 + c_off;
  float s = 0.f;
  const float* wp = wT + (size_t)kq * 512 * 128 + c;
  const float4* ep = (const float4*)(e + kq * 512);
#pragma unroll 4
  for (int j = 0; j < 128; ++j) {
    float4 ev = ep[j];
    s = fmaf(ev.x, wp[(4 * j + 0) * 128], s);
    s = fmaf(ev.y, wp[(4 * j + 1) * 128], s);
    s = fmaf(ev.z, wp[(4 * j + 2) * 128], s);
    s = fmaf(ev.w, wp[(4 * j + 3) * 128], s);
  }
  s += __shfl_xor(s, 16, 64);
  s += __shfl_xor(s, 32, 64);
  if (lane < 16) {
    float v = s + bias[c];
    v = v > 0.f ? v : 0.f;
    int dst;
    if (i < 32) dst = i * 7 + 6;
    else { int wd = i - 32; dst = (wd / 6) * 7 + (wd % 6); }
    all_emb[dst * 128 + c] = v;
  }
}

// ---------------- gemm7 helper for SA ----------------
template <int NCOLS, int RELU, bool RES>
__device__ __forceinline__ void gemm7(const float* __restrict__ X,
                                      const float* __restrict__ WT,
                                      const float* __restrict__ bias,
                                      const float* __restrict__ res,
                                      float* __restrict__ Y, int t) {
  int wv = t >> 6, lane = t & 63;
  int c_off = lane & 15, kq = lane >> 4;
  const int NCH = NCOLS / 16;
  for (int ch = wv; ch < NCH; ch += 16) {
    int c = ch * 16 + c_off;
    float s[7] = {0.f, 0.f, 0.f, 0.f, 0.f, 0.f, 0.f};
    const float* wp = WT + kq * 32 * NCOLS + c;
#pragma unroll 4
    for (int j = 0; j < 8; ++j) {
      float w0 = wp[(4 * j + 0) * NCOLS];
      float w1 = wp[(4 * j + 1) * NCOLS];
      float w2 = wp[(4 * j + 2) * NCOLS];
      float w3 = wp[(4 * j + 3) * NCOLS];
#pragma unroll
      for (int l = 0; l < 7; ++l) {
        float4 xv = *(const float4*)&X[l * 128 + kq * 32 + 4 * j];
        s[l] = fmaf(xv.x, w0, s[l]);
        s[l] = fmaf(xv.y, w1, s[l]);
        s[l] = fmaf(xv.z, w2, s[l]);
        s[l] = fmaf(xv.w, w3, s[l]);
      }
    }
#pragma unroll
    for (int l = 0; l < 7; ++l) {
      s[l] += __shfl_xor(s[l], 16, 64);
      s[l] += __shfl_xor(s[l], 32, 64);
    }
    if (lane < 16) {
      float bv = bias[c];
#pragma unroll
      for (int l = 0; l < 7; ++l) {
        float v = s[l] + bv;
        if (RES) v += res[l * 128 + c];
        if (RELU) v = v > 0.f ? v : 0.f;
        Y[l * NCOLS + c] = v;
      }
    }
  }
}

// ---------------- 3x SA layers + final fc ----------------
__global__ __launch_bounds__(1024) void sa_kernel(
    const float* __restrict__ all_emb, const float* __restrict__ inT,
    const float* __restrict__ in_b, const float* __restrict__ outT,
    const float* __restrict__ out_b, const float* __restrict__ ln1w,
    const float* __restrict__ ln1b, const float* __restrict__ f1T,
    const float* __restrict__ f1b, const float* __restrict__ f2T,
    const float* __restrict__ f2b, const float* __restrict__ ln2w,
    const float* __restrict__ ln2b, const float* __restrict__ fcw,
    const float* __restrict__ fcb, float* __restrict__ out) {
  int b = blockIdx.x, t = threadIdx.x;
  __shared__ float x[7][128], qkv[7][384], att[4][7][7], ybuf[7][128], tmp[7][128];
  __shared__ float mu[7], inv[7];
  if (t < 896) x[t / 128][t % 128] = all_emb[b * 896 + t];
  __syncthreads();
  for (int layer = 0; layer < 3; ++layer) {
    gemm7<384, 0, false>(&x[0][0], inT + layer * 384 * 128, in_b + layer * 384,
                         nullptr, &qkv[0][0], t);
    __syncthreads();
    if (t < 196) {
      int h = t / 49, l = (t % 49) / 7, m = t % 7;
      const float4* qr = (const float4*)&qkv[l][h * 32];
      const float4* kr = (const float4*)&qkv[m][128 + h * 32];
      float s = 0.f;
#pragma unroll
      for (int d = 0; d < 8; ++d) {
        float4 a = qr[d], c = kr[d];
        s += a.x * c.x + a.y * c.y + a.z * c.z + a.w * c.w;
      }
      att[h][l][m] = s * 0.17677669529663687f;
    }
    __syncthreads();
    if (t < 28) {
      int h = t / 7, l = t % 7;
      float mx = att[h][l][0];
      for (int m = 1; m < 7; ++m) mx = fmaxf(mx, att[h][l][m]);
      float s = 0.f;
      float e[7];
      for (int m = 0; m < 7; ++m) { e[m] = expf(att[h][l][m] - mx); s += e[m]; }
      float r = 1.0f / s;
      for (int m = 0; m < 7; ++m) att[h][l][m] = e[m] * r;
    }
    __syncthreads();
    if (t < 896) {
      int l = t / 128, d = t % 128, h = d / 32;
      float s = 0.f;
#pragma unroll
      for (int m = 0; m < 7; ++m) s += att[h][l][m] * qkv[m][256 + d];
      ybuf[l][d] = s;
    }
    __syncthreads();
    gemm7<128, 0, true>(&ybuf[0][0], outT + layer * 128 * 128,
                        out_b + layer * 128, &x[0][0], &tmp[0][0], t);
    __syncthreads();
    if (t < 448) {
      int row = t >> 6, lane = t & 63;
      float a = tmp[row][lane], c2 = tmp[row][lane + 64];
      float s = a + c2;
      for (int o = 1; o < 64; o <<= 1) s += __shfl_xor(s, o, 64);
      float m = s * (1.0f / 128.0f);
      float d1 = a - m, d2 = c2 - m;
      float v = d1 * d1 + d2 * d2;
      for (int o = 1; o < 64; o <<= 1) v += __shfl_xor(v, o, 64);
      if (lane == 0) { mu[row] = m; inv[row] = 1.0f / sqrtf(v * (1.0f / 128.0f) + 1e-5f); }
    }
    __syncthreads();
    if (t < 896) {
      int l = t / 128, d = t % 128;
      x[l][d] = (tmp[l][d] - mu[l]) * inv[l] * ln1w[layer * 128 + d] +
                ln1b[layer * 128 + d];
    }
    __syncthreads();
    gemm7<128, 1, false>(&x[0][0], f1T + layer * 128 * 128, f1b + layer * 128,
                         nullptr, &ybuf[0][0], t);
    __syncthreads();
    gemm7<128, 0, true>(&ybuf[0][0], f2T + layer * 128 * 128, f2b + layer * 128,
                        &x[0][0], &tmp[0][0], t);
    __syncthreads();
    if (t < 448) {
      int row = t >> 6, lane = t & 63;
      float a = tmp[row][lane], c2 = tmp[row][lane + 64];
      float s = a + c2;
      for (int o = 1; o < 64; o <<= 1) s += __shfl_xor(s, o, 64);
      float m = s * (1.0f / 128.0f);
      float d1 = a - m, d2 = c2 - m;
      float v = d1 * d1 + d2 * d2;
      for (int o = 1; o < 64; o <<= 1) v += __shfl_xor(v, o, 64);
      if (lane == 0) { mu[row] = m; inv[row] = 1.0f / sqrtf(v * (1.0f / 128.0f) + 1e-5f); }
    }
    __syncthreads();
    if (t < 896) {
      int l = t / 128, d = t % 128;
      x[l][d] = (tmp[l][d] - mu[l]) * inv[l] * ln2w[layer * 128 + d] +
                ln2b[layer * 128 + d];
    }
    __syncthreads();
  }
  if (t < 64) {
    float s = x[6][t] * fcw[t] + x[6][t + 64] * fcw[t + 64];
    for (int o = 1; o < 64; o <<= 1) s += __shfl_xor(s, o, 64);
    if (t == 0) out[b] = s + fcb[0];
  }
}

extern "C" void kernel_launch(void* const* d_in, const int* in_sizes, int n_in,
                              void* d_out, int out_size, void* d_ws, size_t ws_size,
                              hipStream_t stream) {
  (void)in_sizes; (void)n_in; (void)out_size; (void)ws_size;
  const float* input_img = (const float*)d_in[0];
  const float* cropped = (const float*)d_in[1];
  const float* scale = (const float*)d_in[2];
  const float* conv_w = (const float*)d_in[3];
  const float* fc1_w = (const float*)d_in[4];
  const float* fc1_b = (const float*)d_in[5];
  const float* fc_w = (const float*)d_in[6];
  const float* fc_b = (const float*)d_in[7];
  const float* sa_in_w = (const float*)d_in[8];
  const float* sa_in_b = (const float*)d_in[9];
  const float* sa_out_w = (const float*)d_in[10];
  const float* sa_out_b = (const float*)d_in[11];
  const float* sa_ln1_w = (const float*)d_in[12];
  const float* sa_ln1_b = (const float*)d_in[13];
  const float* sa_fc1_w = (const float*)d_in[14];
  const float* sa_fc1_b = (const float*)d_in[15];
  const float* sa_fc2_w = (const float*)d_in[16];
  const float* sa_fc2_b = (const float*)d_in[17];
  const float* sa_ln2_w = (const float*)d_in[18];
  const float* sa_ln2_b = (const float*)d_in[19];

  char* ws = (char*)d_ws;
  size_t off = 0;
  auto alloc = [&](size_t bytes) -> void* {
    void* p = ws + off;
    off = (off + bytes + 255) & ~(size_t)255;
    return p;
  };
  unsigned short* wcat = (unsigned short*)alloc(2048L * 6144 * 2);
  unsigned short* acat = (unsigned short*)alloc(1568L * 6144 * 2);
  unsigned short* winbuf = (unsigned short*)alloc(9408L * 3072 * 2);
  float* Cpart = (float*)alloc(3L * 1568 * 2048 * 4);
  float* emb = (float*)alloc(224L * 2048 * 4);
  float* fmpart = (float*)alloc(1568L * 32 * 4);
  int* tlbuf = (int*)alloc(32L * 6 * 2 * 4);
  float* all_emb = (float*)alloc(32L * 7 * 128 * 4);
  float* fc1T = (float*)alloc(2048L * 128 * 4);
  float* inT = (float*)alloc(3L * 384 * 128 * 4);
  float* outT = (float*)alloc(3L * 128 * 128 * 4);
  float* f1T = (float*)alloc(3L * 128 * 128 * 4);
  float* f2T = (float*)alloc(3L * 128 * 128 * 4);

  // zero windows-GAP accumulation region (emb rows 32..223)
  hipMemsetAsync(emb + 32 * 2048, 0, 192L * 2048 * 4, stream);

  split_wcat<<<3072, 256, 0, stream>>>(conv_w, wcat);
  patchify_split<<<2352, 256, 0, stream>>>(cropped, acat);
  transpose_all<<<544, 256, 0, stream>>>(fc1_w, fc1T, sa_in_w, inT, sa_out_w,
                                         outT, sa_fc1_w, f1T, sa_fc2_w, f2T);

  // cropped conv: 3 uniform precision planes (round-7 proven config)
  gemm_conv<0><<<dim3(16, 13, 3), 256, 0, stream>>>(acat, wcat, Cpart, nullptr, 1568);
  crop_reduce<<<dim3(32, 8), 256, 0, stream>>>(Cpart, emb, fmpart);
  coords_kernel<<<32, 64, 0, stream>>>(fmpart, scale, tlbuf);
  gather_windows<<<14112, 256, 0, stream>>>(input_img, tlbuf, winbuf);
  // windows conv: single bf16 pass, fused relu+GAP, round-7 mapping (no swizzle)
  gemm_conv<1><<<dim3(16, 74), 256, 0, stream>>>(winbuf, wcat, nullptr, emb, 9408);
  fc1_kernel<<<224, 512, 0, stream>>>(emb, fc1T, fc1_b, all_emb);
  sa_kernel<<<32, 1024, 0, stream>>>(all_emb, inT, sa_in_b, outT, sa_out_b,
                                     sa_ln1_w, sa_ln1_b, f1T, sa_fc1_b,
                                     f2T, sa_fc2_b, sa_ln2_w, sa_ln2_b,
                                     fc_w, fc_b, (float*)d_out);
}

// Round 10
// 374.662 us; speedup vs baseline: 1.2120x; 1.1258x over previous
//
#include <hip/hip_runtime.h>

typedef __attribute__((ext_vector_type(8))) short s16x8;
typedef __attribute__((ext_vector_type(4))) float f32x4;

__device__ __forceinline__ unsigned short f2bf(float x) {
  unsigned int u = __float_as_uint(x);
  u += 0x7FFFu + ((u >> 16) & 1u);
  return (unsigned short)(u >> 16);
}

__device__ __forceinline__ void gload16(const unsigned short* g, unsigned short* l) {
  __builtin_amdgcn_global_load_lds(
      (const __attribute__((address_space(1))) void*)g,
      (__attribute__((address_space(3))) void*)l, 16, 0, 0);
}

// ---------------- weights fp32 -> Whi[2048][3072] bf16 ----------------
__global__ __launch_bounds__(256) void split_whi(const float* __restrict__ src,
                                                 unsigned short* __restrict__ whi) {
  int idx = blockIdx.x * 256 + threadIdx.x;  // 2048*384
  if (idx >= 2048 * 384) return;
  const float4* s = (const float4*)(src + (size_t)idx * 8);
  float4 v0 = s[0], v1 = s[1];
  unsigned short h8[8] = {f2bf(v0.x), f2bf(v0.y), f2bf(v0.z), f2bf(v0.w),
                          f2bf(v1.x), f2bf(v1.y), f2bf(v1.z), f2bf(v1.w)};
  *(uint4*)&whi[(size_t)idx * 8] = *(const uint4*)h8;
}

// ---------------- patchify cropped -> Apat[1568][3072] bf16 ----------------
__global__ __launch_bounds__(256) void patchify_hi(
    const float* __restrict__ src, unsigned short* __restrict__ apat) {
  int idx = blockIdx.x * 256 + threadIdx.x;  // 1568*384
  if (idx >= 1568 * 384) return;
  int kseg = idx % 384, row = idx / 384;
  int img = row / 49, pos = row % 49;
  int k = kseg * 8;
  int c = k >> 10, rem = k & 1023, r = rem >> 5, x0 = rem & 31;
  const float* s =
      src + ((size_t)(img * 3 + c) * 224 + (pos / 7) * 32 + r) * 224 +
      (pos % 7) * 32 + x0;
  float4 v0 = *(const float4*)(s);
  float4 v1 = *(const float4*)(s + 4);
  unsigned short h8[8] = {f2bf(v0.x), f2bf(v0.y), f2bf(v0.z), f2bf(v0.w),
                          f2bf(v1.x), f2bf(v1.y), f2bf(v1.z), f2bf(v1.w)};
  *(uint4*)&apat[(size_t)row * 3072 + k] = *(const uint4*)h8;
}

// ---------------- window crop/resize -> patchified bf16 [9408][3072] ----------------
__global__ __launch_bounds__(256) void gather_windows(
    const float* __restrict__ img, const int* __restrict__ tl,
    unsigned short* __restrict__ win) {
  int idx = blockIdx.x * 256 + threadIdx.x;  // 9408*384
  if (idx >= 9408 * 384) return;
  int kseg = idx % 384, row = idx / 384;
  int w = row / 49, pos = row % 49;
  int b = w / 6, p = w % 6;
  int k = kseg * 8;
  int c = k >> 10, rem = k & 1023, r = rem >> 5, x0 = rem & 31;
  int y = (pos / 7) * 32 + r;
  int xb = (pos % 7) * 32 + x0;
  int tly = tl[(b * 6 + p) * 2 + 0];
  int tlx = tl[(b * 6 + p) * 2 + 1];
  const float* im = img + (size_t)(b * 3 + c) * 448 * 448;
  unsigned short o8[8];
  if (p < 3) {
    const float* s = im + (size_t)(tly + y) * 448 + tlx + xb;
#pragma unroll
    for (int i = 0; i < 8; ++i) o8[i] = f2bf(s[i]);
  } else {
    const float f = 111.0f / 223.0f;
    float sy = tly + y * f;
    int y0 = (int)floorf(sy);
    float wy = sy - (float)y0;
    int y1 = y0 + 1 < 447 ? y0 + 1 : 447;
    const float* r0p = im + (size_t)y0 * 448;
    const float* r1p = im + (size_t)y1 * 448;
#pragma unroll
    for (int i = 0; i < 8; ++i) {
      float sx = tlx + (xb + i) * f;
      int x0i = (int)floorf(sx);
      float wx = sx - (float)x0i;
      int x1i = x0i + 1 < 447 ? x0i + 1 : 447;
      float v0 = r0p[x0i] * (1.f - wy) + r1p[x0i] * wy;
      float v1 = r0p[x1i] * (1.f - wy) + r1p[x1i] * wy;
      o8[i] = f2bf(v0 * (1.f - wx) + v1 * wx);
    }
  }
  *(uint4*)&win[(size_t)row * 3072 + k] = *(const uint4*)o8;
}

// ---------------- all weight transposes in ONE dispatch (544 blocks) ----------------
__global__ __launch_bounds__(256) void transpose_all(
    const float* __restrict__ fc1_w, float* __restrict__ fc1T,
    const float* __restrict__ in_w, float* __restrict__ inT,
    const float* __restrict__ out_w, float* __restrict__ outT,
    const float* __restrict__ f1w, float* __restrict__ f1T,
    const float* __restrict__ f2w, float* __restrict__ f2T) {
  __shared__ float tile[32][33];
  int id = blockIdx.x;
  const float* src;
  float* dst;
  int R, C, bx, by;
  if (id < 256) {
    src = fc1_w; dst = fc1T; R = 128; C = 2048; bx = id % 64; by = id / 64;
  } else if (id < 400) {
    id -= 256;
    int z = id / 48, r = id % 48;
    src = in_w + z * 384 * 128; dst = inT + z * 384 * 128;
    R = 384; C = 128; bx = r % 4; by = r / 4;
  } else {
    id -= 400;
    int which = id / 48;  // 0=out, 1=f1, 2=f2
    id -= which * 48;
    int z = id / 16, r = id % 16;
    const float* s3[3] = {out_w, f1w, f2w};
    float* d3[3] = {outT, f1T, f2T};
    src = s3[which] + z * 128 * 128; dst = d3[which] + z * 128 * 128;
    R = 128; C = 128; bx = r % 4; by = r / 4;
  }
  int t = threadIdx.x;
  int tx = t & 31, ty = t >> 5;  // 32 x 8
#pragma unroll
  for (int i = 0; i < 32; i += 8) {
    int r = by * 32 + ty + i, c = bx * 32 + tx;
    if (r < R && c < C) tile[ty + i][tx] = src[(size_t)r * C + c];
  }
  __syncthreads();
#pragma unroll
  for (int i = 0; i < 32; i += 8) {
    int r = bx * 32 + ty + i, c = by * 32 + tx;
    if (r < C && c < R) dst[(size_t)r * R + c] = tile[tx][ty + i];
  }
}

// ---------------- conv GEMM (m97 structure) + fused relu/GAP/fm epilogue ----------
// C[M][2048] = A[M][3072] @ Whi[2048][3072]^T, single bf16 pass.
// Epilogue: relu; windowed GAP -> atomicAdd(emb[embBase + r/49][col], v/49);
// MODE 0 additionally: per-row channel sums -> atomicAdd(fm[r], .) for coords.
template <int MODE>
__global__ __launch_bounds__(256) void gemm_conv(
    const unsigned short* __restrict__ A, const unsigned short* __restrict__ W,
    float* __restrict__ embOut, float* __restrict__ fm, int M) {
  constexpr int embBase = MODE ? 32 : 0;
  __shared__ unsigned short sA[128 * 64];
  __shared__ unsigned short sB[128 * 64];
  const int t = threadIdx.x;
  const int nb = blockIdx.x, mb = blockIdx.y;
  const int lane = t & 63;
  const int lr = lane & 15, lk = lane >> 4;
  const int wv = t >> 6;
  const int wqr = wv >> 1, wqc = wv & 1;

  const unsigned short* gA[4];
  unsigned short* lA[4];
  const unsigned short* gB[4];
  unsigned short* lB[4];
#pragma unroll
  for (int j = 0; j < 4; ++j) {
    int chunk = j * 256 + t;
    int row = chunk >> 3, seg = chunk & 7;
    int gseg = seg ^ (row & 7);
    int rg = mb * 128 + row;
    if (rg > M - 1) rg = M - 1;
    gA[j] = A + (size_t)rg * 3072 + gseg * 8;
    lA[j] = &sA[chunk * 8];
    gB[j] = W + (size_t)(nb * 128 + row) * 3072 + gseg * 8;
    lB[j] = &sB[chunk * 8];
  }

  f32x4 acc[4][4] = {};
  for (int kb = 0; kb < 48; ++kb) {
    if (kb) __syncthreads();
#pragma unroll
    for (int j = 0; j < 4; ++j) {
      gload16(gA[j] + kb * 64, lA[j]);
      gload16(gB[j] + kb * 64, lB[j]);
    }
    __syncthreads();
#pragma unroll
    for (int ks = 0; ks < 2; ++ks) {
      s16x8 a[4], b[4];
#pragma unroll
      for (int m = 0; m < 4; ++m) {
        int row = wqr * 64 + m * 16 + lr;
        int seg = ks * 4 + lk;
        a[m] = *(const s16x8*)&sA[row * 64 + ((seg ^ (row & 7)) * 8)];
      }
#pragma unroll
      for (int n = 0; n < 4; ++n) {
        int row = wqc * 64 + n * 16 + lr;
        int seg = ks * 4 + lk;
        b[n] = *(const s16x8*)&sB[row * 64 + ((seg ^ (row & 7)) * 8)];
      }
#pragma unroll
      for (int m = 0; m < 4; ++m)
#pragma unroll
        for (int n = 0; n < 4; ++n)
          acc[m][n] =
              __builtin_amdgcn_mfma_f32_16x16x32_bf16(a[m], b[n], acc[m][n], 0, 0, 0);
    }
  }

  // relu + row-validity
  float rv[4][4][4];
#pragma unroll
  for (int m = 0; m < 4; ++m) {
    int base = mb * 128 + wqr * 64 + m * 16;
#pragma unroll
    for (int e = 0; e < 4; ++e) {
      int r = base + lk * 4 + e;
      bool ok = (r < M);
#pragma unroll
      for (int n = 0; n < 4; ++n) {
        float v = acc[m][n][e];
        v = v > 0.f ? v : 0.f;
        rv[m][n][e] = ok ? v : 0.f;
      }
    }
  }

  // windowed GAP -> emb
#pragma unroll
  for (int m = 0; m < 4; ++m) {
    int base = mb * 128 + wqr * 64 + m * 16;
    if (base >= M) continue;
    int w0 = base / 49;
    int rtop = base + 15;
    if (rtop > M - 1) rtop = M - 1;
    int w1 = rtop / 49;
    for (int w = w0; w <= w1; ++w) {
#pragma unroll
      for (int n = 0; n < 4; ++n) {
        float s = 0.f;
#pragma unroll
        for (int e = 0; e < 4; ++e) {
          int r = base + lk * 4 + e;
          s += (r < M && (r / 49) == w) ? rv[m][n][e] : 0.f;
        }
        s += __shfl_xor(s, 16, 64);
        s += __shfl_xor(s, 32, 64);
        if (lk == 0)
          atomicAdd(&embOut[(size_t)(embBase + w) * 2048 + nb * 128 + wqc * 64 +
                            n * 16 + lr],
                    s * (1.0f / 49.0f));
      }
    }
  }

  // MODE 0: per-row channel partial sums -> fm (feeds coords argmax)
  if (MODE == 0) {
#pragma unroll
    for (int m = 0; m < 4; ++m) {
      int base = mb * 128 + wqr * 64 + m * 16;
#pragma unroll
      for (int e = 0; e < 4; ++e) {
        int r = base + lk * 4 + e;
        float v = rv[m][0][e] + rv[m][1][e] + rv[m][2][e] + rv[m][3][e];
        v += __shfl_xor(v, 1, 64);
        v += __shfl_xor(v, 2, 64);
        v += __shfl_xor(v, 4, 64);
        v += __shfl_xor(v, 8, 64);
        if (lr == 0 && r < M) atomicAdd(&fm[r], v);
      }
    }
  }
}

// ---------------- coordinates (NMS peak picking) ----------------
__global__ void coords_kernel(const float* __restrict__ fm,
                              const float* __restrict__ scale,
                              int* __restrict__ tl) {
  int b = blockIdx.x, t = threadIdx.x;
  __shared__ float fs[49];
  if (t < 49) fs[t] = fm[b * 49 + t];
  __syncthreads();
  if (t != 0) return;
  int s0 = (int)scale[b * 2 + 0], s1 = (int)scale[b * 2 + 1];
  int smin = s0 < s1 ? s0 : s1;
  int base_y = (s0 - smin) / 2, base_x = (s1 - smin) / 2;
  float sc[36];
  for (int f = 0; f < 2; ++f) {
    int kk = (f == 0) ? 3 : 2;
    int sw = 8 - kk;
    int psz = (f == 0) ? 224 : 112;
    int half = psz / 2;
    for (int iy = 0; iy < sw; ++iy)
      for (int ix = 0; ix < sw; ++ix) {
        float s = 0.f;
        for (int dy = 0; dy < kk; ++dy)
          for (int dx = 0; dx < kk; ++dx) s += fs[(iy + dy) * 7 + ix + dx];
        sc[iy * sw + ix] = s / (float)(kk * kk);
      }
    for (int it = 0; it < 3; ++it) {
      float best = -1e30f;
      int bi = 0;
      for (int i = 0; i < sw * sw; ++i)
        if (sc[i] > best) { best = sc[i]; bi = i; }
      int ly = bi / sw, lx = bi % sw;
      for (int dy = -1; dy <= 1; ++dy)
        for (int dx = -1; dx <= 1; ++dx) {
          int ny = ly + dy, nx = lx + dx;
          if (ny >= 0 && ny < sw && nx >= 0 && nx < sw) sc[ny * sw + nx] = 0.f;
        }
      float rh = (2 * ly + 7 - sw + 1) / 14.0f;
      float rw = (2 * lx + 7 - sw + 1) / 14.0f;
      int cy = (int)(base_y + smin * rh);
      int cx = (int)(base_x + smin * rw);
      int tly = cy - half, bry = cy + half;
      int tlx = cx - half, brx = cx + half;
      int below = tly < 0 ? tly : 0; bry -= below; tly -= below;
      int over = bry - s0 > 0 ? bry - s0 : 0; tly -= over; bry -= over;
      tly = tly > 0 ? tly : 0;
      below = tlx < 0 ? tlx : 0; brx -= below; tlx -= below;
      over = brx - s1 > 0 ? brx - s1 : 0; tlx -= over; brx -= over;
      tlx = tlx > 0 ? tlx : 0;
      int slot = f * 3 + it;
      tl[(b * 6 + slot) * 2 + 0] = tly;
      tl[(b * 6 + slot) * 2 + 1] = tlx;
    }
  }
}

// ---------------- fc1 + relu + reorg to all_emb[32,7,128] ----------------
__global__ __launch_bounds__(512) void fc1_kernel(const float* __restrict__ emb,
                                                  const float* __restrict__ wT,
                                                  const float* __restrict__ bias,
                                                  float* __restrict__ all_emb) {
  int i = blockIdx.x;
  __shared__ float e[2048];
  int t = threadIdx.x;
  ((float4*)e)[t] = ((const float4*)(emb + (size_t)i * 2048))[t];
  __syncthreads();
  int wv = t >> 6, lane = t & 63;
  int c_off = lane & 15, kq = lane >> 4;
  int c = wv * 16 + c_off;
  float s = 0.f;
  const float* wp = wT + (size_t)kq * 512 * 128 + c;
  const float4* ep = (const float4*)(e + kq * 512);
#pragma unroll 4
  for (int j = 0; j < 128; ++j) {
    float4 ev = ep[j];
    s = fmaf(ev.x, wp[(4 * j + 0) * 128], s);
    s = fmaf(ev.y, wp[(4 * j + 1) * 128], s);
    s = fmaf(ev.z, wp[(4 * j + 2) * 128], s);
    s = fmaf(ev.w, wp[(4 * j + 3) * 128], s);
  }
  s += __shfl_xor(s, 16, 64);
  s += __shfl_xor(s, 32, 64);
  if (lane < 16) {
    float v = s + bias[c];
    v = v > 0.f ? v : 0.f;
    int dst;
    if (i < 32) dst = i * 7 + 6;
    else { int wd = i - 32; dst = (wd / 6) * 7 + (wd % 6); }
    all_emb[dst * 128 + c] = v;
  }
}

// ---------------- gemm7 helper for SA ----------------
template <int NCOLS, int RELU, bool RES>
__device__ __forceinline__ void gemm7(const float* __restrict__ X,
                                      const float* __restrict__ WT,
                                      const float* __restrict__ bias,
                                      const float* __restrict__ res,
                                      float* __restrict__ Y, int t) {
  int wv = t >> 6, lane = t & 63;
  int c_off = lane & 15, kq = lane >> 4;
  const int NCH = NCOLS / 16;
  for (int ch = wv; ch < NCH; ch += 16) {
    int c = ch * 16 + c_off;
    float s[7] = {0.f, 0.f, 0.f, 0.f, 0.f, 0.f, 0.f};
    const float* wp = WT + kq * 32 * NCOLS + c;
#pragma unroll 4
    for (int j = 0; j < 8; ++j) {
      float w0 = wp[(4 * j + 0) * NCOLS];
      float w1 = wp[(4 * j + 1) * NCOLS];
      float w2 = wp[(4 * j + 2) * NCOLS];
      float w3 = wp[(4 * j + 3) * NCOLS];
#pragma unroll
      for (int l = 0; l < 7; ++l) {
        float4 xv = *(const float4*)&X[l * 128 + kq * 32 + 4 * j];
        s[l] = fmaf(xv.x, w0, s[l]);
        s[l] = fmaf(xv.y, w1, s[l]);
        s[l] = fmaf(xv.z, w2, s[l]);
        s[l] = fmaf(xv.w, w3, s[l]);
      }
    }
#pragma unroll
    for (int l = 0; l < 7; ++l) {
      s[l] += __shfl_xor(s[l], 16, 64);
      s[l] += __shfl_xor(s[l], 32, 64);
    }
    if (lane < 16) {
      float bv = bias[c];
#pragma unroll
      for (int l = 0; l < 7; ++l) {
        float v = s[l] + bv;
        if (RES) v += res[l * 128 + c];
        if (RELU) v = v > 0.f ? v : 0.f;
        Y[l * NCOLS + c] = v;
      }
    }
  }
}

// ---------------- 3x SA layers + final fc ----------------
__global__ __launch_bounds__(1024) void sa_kernel(
    const float* __restrict__ all_emb, const float* __restrict__ inT,
    const float* __restrict__ in_b, const float* __restrict__ outT,
    const float* __restrict__ out_b, const float* __restrict__ ln1w,
    const float* __restrict__ ln1b, const float* __restrict__ f1T,
    const float* __restrict__ f1b, const float* __restrict__ f2T,
    const float* __restrict__ f2b, const float* __restrict__ ln2w,
    const float* __restrict__ ln2b, const float* __restrict__ fcw,
    const float* __restrict__ fcb, float* __restrict__ out) {
  int b = blockIdx.x, t = threadIdx.x;
  __shared__ float x[7][128], qkv[7][384], att[4][7][7], ybuf[7][128], tmp[7][128];
  __shared__ float mu[7], inv[7];
  if (t < 896) x[t / 128][t % 128] = all_emb[b * 896 + t];
  __syncthreads();
  for (int layer = 0; layer < 3; ++layer) {
    gemm7<384, 0, false>(&x[0][0], inT + layer * 384 * 128, in_b + layer * 384,
                         nullptr, &qkv[0][0], t);
    __syncthreads();
    if (t < 196) {
      int h = t / 49, l = (t % 49) / 7, m = t % 7;
      const float4* qr = (const float4*)&qkv[l][h * 32];
      const float4* kr = (const float4*)&qkv[m][128 + h * 32];
      float s = 0.f;
#pragma unroll
      for (int d = 0; d < 8; ++d) {
        float4 a = qr[d], c = kr[d];
        s += a.x * c.x + a.y * c.y + a.z * c.z + a.w * c.w;
      }
      att[h][l][m] = s * 0.17677669529663687f;
    }
    __syncthreads();
    if (t < 28) {
      int h = t / 7, l = t % 7;
      float mx = att[h][l][0];
      for (int m = 1; m < 7; ++m) mx = fmaxf(mx, att[h][l][m]);
      float s = 0.f;
      float e[7];
      for (int m = 0; m < 7; ++m) { e[m] = expf(att[h][l][m] - mx); s += e[m]; }
      float r = 1.0f / s;
      for (int m = 0; m < 7; ++m) att[h][l][m] = e[m] * r;
    }
    __syncthreads();
    if (t < 896) {
      int l = t / 128, d = t % 128, h = d / 32;
      float s = 0.f;
#pragma unroll
      for (int m = 0; m < 7; ++m) s += att[h][l][m] * qkv[m][256 + d];
      ybuf[l][d] = s;
    }
    __syncthreads();
    gemm7<128, 0, true>(&ybuf[0][0], outT + layer * 128 * 128,
                        out_b + layer * 128, &x[0][0], &tmp[0][0], t);
    __syncthreads();
    if (t < 448) {
      int row = t >> 6, lane = t & 63;
      float a = tmp[row][lane], c2 = tmp[row][lane + 64];
      float s = a + c2;
      for (int o = 1; o < 64; o <<= 1) s += __shfl_xor(s, o, 64);
      float m = s * (1.0f / 128.0f);
      float d1 = a - m, d2 = c2 - m;
      float v = d1 * d1 + d2 * d2;
      for (int o = 1; o < 64; o <<= 1) v += __shfl_xor(v, o, 64);
      if (lane == 0) { mu[row] = m; inv[row] = 1.0f / sqrtf(v * (1.0f / 128.0f) + 1e-5f); }
    }
    __syncthreads();
    if (t < 896) {
      int l = t / 128, d = t % 128;
      x[l][d] = (tmp[l][d] - mu[l]) * inv[l] * ln1w[layer * 128 + d] +
                ln1b[layer * 128 + d];
    }
    __syncthreads();
    gemm7<128, 1, false>(&x[0][0], f1T + layer * 128 * 128, f1b + layer * 128,
                         nullptr, &ybuf[0][0], t);
    __syncthreads();
    gemm7<128, 0, true>(&ybuf[0][0], f2T + layer * 128 * 128, f2b + layer * 128,
                        &x[0][0], &tmp[0][0], t);
    __syncthreads();
    if (t < 448) {
      int row = t >> 6, lane = t & 63;
      float a = tmp[row][lane], c2 = tmp[row][lane + 64];
      float s = a + c2;
      for (int o = 1; o < 64; o <<= 1) s += __shfl_xor(s, o, 64);
      float m = s * (1.0f / 128.0f);
      float d1 = a - m, d2 = c2 - m;
      float v = d1 * d1 + d2 * d2;
      for (int o = 1; o < 64; o <<= 1) v += __shfl_xor(v, o, 64);
      if (lane == 0) { mu[row] = m; inv[row] = 1.0f / sqrtf(v * (1.0f / 128.0f) + 1e-5f); }
    }
    __syncthreads();
    if (t < 896) {
      int l = t / 128, d = t % 128;
      x[l][d] = (tmp[l][d] - mu[l]) * inv[l] * ln2w[layer * 128 + d] +
                ln2b[layer * 128 + d];
    }
    __syncthreads();
  }
  if (t < 64) {
    float s = x[6][t] * fcw[t] + x[6][t + 64] * fcw[t + 64];
    for (int o = 1; o < 64; o <<= 1) s += __shfl_xor(s, o, 64);
    if (t == 0) out[b] = s + fcb[0];
  }
}

extern "C" void kernel_launch(void* const* d_in, const int* in_sizes, int n_in,
                              void* d_out, int out_size, void* d_ws, size_t ws_size,
                              hipStream_t stream) {
  (void)in_sizes; (void)n_in; (void)out_size; (void)ws_size;
  const float* input_img = (const float*)d_in[0];
  const float* cropped = (const float*)d_in[1];
  const float* scale = (const float*)d_in[2];
  const float* conv_w = (const float*)d_in[3];
  const float* fc1_w = (const float*)d_in[4];
  const float* fc1_b = (const float*)d_in[5];
  const float* fc_w = (const float*)d_in[6];
  const float* fc_b = (const float*)d_in[7];
  const float* sa_in_w = (const float*)d_in[8];
  const float* sa_in_b = (const float*)d_in[9];
  const float* sa_out_w = (const float*)d_in[10];
  const float* sa_out_b = (const float*)d_in[11];
  const float* sa_ln1_w = (const float*)d_in[12];
  const float* sa_ln1_b = (const float*)d_in[13];
  const float* sa_fc1_w = (const float*)d_in[14];
  const float* sa_fc1_b = (const float*)d_in[15];
  const float* sa_fc2_w = (const float*)d_in[16];
  const float* sa_fc2_b = (const float*)d_in[17];
  const float* sa_ln2_w = (const float*)d_in[18];
  const float* sa_ln2_b = (const float*)d_in[19];

  char* ws = (char*)d_ws;
  size_t off = 0;
  auto alloc = [&](size_t bytes) -> void* {
    void* p = ws + off;
    off = (off + bytes + 255) & ~(size_t)255;
    return p;
  };
  unsigned short* whi = (unsigned short*)alloc(2048L * 3072 * 2);
  unsigned short* apat = (unsigned short*)alloc(1568L * 3072 * 2);
  unsigned short* winbuf = (unsigned short*)alloc(9408L * 3072 * 2);
  float* emb = (float*)alloc(224L * 2048 * 4);
  float* fm = (float*)alloc(1568L * 4);
  int* tlbuf = (int*)alloc(32L * 6 * 2 * 4);
  float* all_emb = (float*)alloc(32L * 7 * 128 * 4);
  float* fc1T = (float*)alloc(2048L * 128 * 4);
  float* inT = (float*)alloc(3L * 384 * 128 * 4);
  float* outT = (float*)alloc(3L * 128 * 128 * 4);
  float* f1T = (float*)alloc(3L * 128 * 128 * 4);
  float* f2T = (float*)alloc(3L * 128 * 128 * 4);

  // zero GAP/fm accumulation regions (emb and fm are contiguous in ws)
  hipMemsetAsync(emb, 0, 224L * 2048 * 4, stream);
  hipMemsetAsync(fm, 0, 1568L * 4, stream);

  split_whi<<<3072, 256, 0, stream>>>(conv_w, whi);
  patchify_hi<<<2352, 256, 0, stream>>>(cropped, apat);
  transpose_all<<<544, 256, 0, stream>>>(fc1_w, fc1T, sa_in_w, inT, sa_out_w,
                                         outT, sa_fc1_w, f1T, sa_fc2_w, f2T);

  // cropped conv: single bf16 pass, fused relu+GAP(emb rows 0..31)+fm
  gemm_conv<0><<<dim3(16, 13), 256, 0, stream>>>(apat, whi, emb, fm, 1568);
  coords_kernel<<<32, 64, 0, stream>>>(fm, scale, tlbuf);
  gather_windows<<<14112, 256, 0, stream>>>(input_img, tlbuf, winbuf);
  // windows conv: single bf16 pass, fused relu+GAP(emb rows 32..223)
  gemm_conv<1><<<dim3(16, 74), 256, 0, stream>>>(winbuf, whi, emb, nullptr, 9408);
  fc1_kernel<<<224, 512, 0, stream>>>(emb, fc1T, fc1_b, all_emb);
  sa_kernel<<<32, 1024, 0, stream>>>(all_emb, inT, sa_in_b, outT, sa_out_b,
                                     sa_ln1_w, sa_ln1_b, f1T, sa_fc1_b,
                                     f2T, sa_fc2_b, sa_ln2_w, sa_ln2_b,
                                     fc_w, fc_b, (float*)d_out);
}